// Round 2
// 417.848 us; speedup vs baseline: 1.1013x; 1.1013x over previous
//
#include <hip/hip_runtime.h>
#include <math.h>

#define SS 1024
#define DD 1024
#define NB 64
#define NT 34            // 33 tags + BOS
#define NP 48            // padded state count (3 x 16)
#define NC 32            // time chunks per sequence (32 steps each)
#define BOSR 33

typedef __attribute__((ext_vector_type(8))) short bf16x8;
typedef __attribute__((ext_vector_type(4))) float f32x4;

// ---- ws layout (float index) ----
#define WS_BOS   0                              // [65536] proj col 33
#define WS_PMAT  (WS_BOS + NB*SS)               // [64*32*2304] chunk matrices f32
#define WS_CC    (WS_PMAT + NB*NC*NP*NP)        // [2048] chunk log-renorm
#define WS_Z     (WS_CC + NB*NC)                // [64]
#define WS_SC    (WS_Z + NB)                    // [64]
#define WS_BF16  (WS_SC + NB)                   // bf16 region start (ushort*)
// bf16 region (ushort offsets)
#define BW_WT    0                              // Wt[48][1024]: W^T bf16, pad 0
#define BW_ETA   (48*1024)                      // expTA[48][64]: A[m][k]=exp(T[k][m])

__device__ __forceinline__ float warp_sum64(float x) {
  #pragma unroll
  for (int off = 32; off > 0; off >>= 1) x += __shfl_down(x, off, 64);
  return x;
}
__device__ __forceinline__ float rfl(float x) {
  return __int_as_float(__builtin_amdgcn_readfirstlane(__float_as_int(x)));
}
__device__ __forceinline__ unsigned short f2bf(float f) {  // RNE (host-side prep only)
  unsigned int u = __float_as_uint(f);
  unsigned int r = u + 0x7fffu + ((u >> 16) & 1u);
  return (unsigned short)(r >> 16);
}
__device__ __forceinline__ float bf2f(unsigned short h) {
  return __uint_as_float(((unsigned int)h) << 16);
}
// 2x f32 -> packed 2x bf16 in one VALU op (gfx950 v_cvt_pk_bf16_f32, RNE)
__device__ __forceinline__ unsigned int pk_bf16(float a, float b) {
  unsigned int d;
  asm("v_cvt_pk_bf16_f32 %0, %1, %2" : "=v"(d) : "v"(a), "v"(b));
  return d;
}

// ---------------- prep: Wt bf16 transpose + expTA ----------------------------
__global__ __launch_bounds__(256) void prep(const float* __restrict__ W,
                                            const float* __restrict__ T,
                                            unsigned short* __restrict__ bw) {
  int idx = blockIdx.x * 256 + threadIdx.x;
  if (idx < 48 * 1024) {                        // Wt[n][k] = W[k][n]
    int n = idx >> 10, k = idx & 1023;
    float v = (n < NT) ? W[k * NT + n] : 0.0f;
    bw[BW_WT + idx] = f2bf(v);
  } else if (idx < 48 * 1024 + 48 * 64) {       // expTA[m][k] = exp(T[k][m])
    int j = idx - 48 * 1024;
    int m = j >> 6, k = j & 63;
    float v = (m < NT && k < NT) ? __expf(T[k * NT + m]) : 0.0f;
    bw[BW_ETA + j] = f2bf(v);
  }
}

// ---------------- GEMM: proj = em @ W + b  (bf16 MFMA, mem-bound) ------------
// 512 blocks x 256 thr; block = 128 rows; wave w: rows w*32..+31 (2 Mtiles),
// 3 Ntiles (48 cols). em f32 -> bf16 staged via double-buffered LDS; W from
// precomputed bf16 Wt (global, L2-resident) prefetched into B-frags.
__global__ __launch_bounds__(256) void gemm_mfma(
    const float* __restrict__ em, const unsigned short* __restrict__ bw,
    const float* __restrict__ bias,
    float* __restrict__ logits, float* __restrict__ bos) {
  __shared__ unsigned short At[2][128][40];     // row stride 40 bf16: 2-way max
  const int tid = threadIdx.x;
  const int lane = tid & 63, wv = tid >> 6;
  const int q = lane >> 4, l15 = lane & 15;
  const size_t row0 = (size_t)blockIdx.x * 128;
  const unsigned short* Wt = bw + BW_WT;
  const f32x4* g4 = (const f32x4*)(em + row0 * DD);

  f32x4 acc[2][3];
  f32x4 z4 = {0.f, 0.f, 0.f, 0.f};
  #pragma unroll
  for (int mt = 0; mt < 2; ++mt)
    #pragma unroll
    for (int nt = 0; nt < 3; ++nt) acc[mt][nt] = z4;

  int sr[4], sq[4];
  #pragma unroll
  for (int i = 0; i < 4; ++i) { int s = tid + i * 256; sr[i] = s >> 3; sq[i] = s & 7; }

  f32x4 pf[4];
  #pragma unroll
  for (int i = 0; i < 4; ++i)
    pf[i] = __builtin_nontemporal_load(g4 + sr[i] * 256 + sq[i]);
  bf16x8 Bf[3], Bn[3];
  #pragma unroll
  for (int nt = 0; nt < 3; ++nt)
    Bf[nt] = *(const bf16x8*)(Wt + (nt * 16 + l15) * 1024 + q * 8);

  for (int c = 0; c < 32; ++c) {
    #pragma unroll
    for (int i = 0; i < 4; ++i) {               // stage chunk c (cvt_pk -> b64)
      uint2 pk;
      pk.x = pk_bf16(pf[i][0], pf[i][1]);
      pk.y = pk_bf16(pf[i][2], pf[i][3]);
      *(uint2*)&At[c & 1][sr[i]][sq[i] * 4] = pk;
    }
    int cn = (c + 1 < 32) ? c + 1 : c;          // prefetch chunk c+1
    #pragma unroll
    for (int i = 0; i < 4; ++i)
      pf[i] = __builtin_nontemporal_load(g4 + sr[i] * 256 + cn * 8 + sq[i]);
    #pragma unroll
    for (int nt = 0; nt < 3; ++nt)
      Bn[nt] = *(const bf16x8*)(Wt + (nt * 16 + l15) * 1024 + cn * 32 + q * 8);
    __syncthreads();
    bf16x8 Af[2];
    #pragma unroll
    for (int mt = 0; mt < 2; ++mt)
      Af[mt] = *(const bf16x8*)&At[c & 1][wv * 32 + mt * 16 + l15][q * 8];
    #pragma unroll
    for (int mt = 0; mt < 2; ++mt)
      #pragma unroll
      for (int nt = 0; nt < 3; ++nt)
        acc[mt][nt] = __builtin_amdgcn_mfma_f32_16x16x32_bf16(
            Af[mt], Bf[nt], acc[mt][nt], 0, 0, 0);
    #pragma unroll
    for (int nt = 0; nt < 3; ++nt) Bf[nt] = Bn[nt];
  }

  // epilogue: + bias, store cols<33 to logits, col 33 to bos
  #pragma unroll
  for (int nt = 0; nt < 3; ++nt) {
    int col = nt * 16 + l15;
    float bj = (col < NT) ? bias[col] : 0.0f;
    #pragma unroll
    for (int mt = 0; mt < 2; ++mt) {
      #pragma unroll
      for (int r = 0; r < 4; ++r) {
        float v = acc[mt][nt][r] + bj;
        size_t rg = row0 + wv * 32 + mt * 16 + q * 4 + r;
        if (col < 33) logits[rg * 33 + col] = v;
        else if (col == 33) bos[rg] = v;
      }
    }
  }
}

// ---------------- chunk transfer matrices (MFMA) + score ---------------------
// blocks 0..2047: (b,c) chunk matrix (32 steps), 1 wave. blocks 2048..: score.
// Recurrence (transposed): rows scaled by ee, renorm scalar every step.
// Storage S[n][k] = P[n][k] serves as B-operand (k-contig) AND receives D
// natively (lane col n fixed, 4 contig rows -> k) via ds_write_b64.
__global__ __launch_bounds__(64) void chains_mat(
    const float* __restrict__ logits, const float* __restrict__ bos,
    const unsigned short* __restrict__ bw, const float* __restrict__ mask,
    const float* __restrict__ T, const int* __restrict__ tags,
    float* __restrict__ Pmat, float* __restrict__ CC,
    float* __restrict__ scorearr) {
  const int blk = blockIdx.x, lane = threadIdx.x;
  if (blk >= NB * NC) {                         // ---- supervised score ----
    int b = blk - NB * NC;
    float local = 0.0f;
    for (int t = lane; t < SS; t += 64) {
      if (t == 0) {
        int tg = tags[b * SS];
        local += T[BOSR * NT + tg] + logits[(size_t)(b * SS) * 33 + tg];
      } else {
        int tg = tags[b * SS + t];
        int tp = tags[b * SS + t - 1];
        float m = mask[b * SS + t];
        local += m * (logits[(size_t)(b * SS + t) * 33 + tg] + T[tp * NT + tg]);
      }
    }
    float w = warp_sum64(local);
    if (lane == 0) scorearr[b] = w;
    return;
  }

  __shared__ unsigned short S[48][72];          // P bf16, stride 72 (2-way max)
  __shared__ float eeL[32][52];                 // exp(emissions), 16B-aligned rows
  const int b = blk >> 5, c = blk & 31;
  const int q = lane >> 4, l15 = lane & 15;

  {                                             // zero S then identity
    unsigned long long* p = (unsigned long long*)&S[0][0];   // 864 qwords
    for (int i = lane; i < 864; i += 64) p[i] = 0ull;
  }
  __syncthreads();
  if (lane < NT) S[lane][lane] = 0x3F80;        // bf16(1.0)

  int t = c * 32 + 1 + lane;                    // lanes 0..31 own one step each
  float mval = 0.0f;
  if (lane < 32) {
    if (t < SS) {
      size_t rg = (size_t)b * SS + t;
      #pragma unroll
      for (int j = 0; j < 33; ++j) eeL[lane][j] = __expf(logits[rg * 33 + j]);
      eeL[lane][33] = __expf(bos[rg]);
      #pragma unroll
      for (int j = 34; j < 48; ++j) eeL[lane][j] = 0.0f;
      mval = mask[rg];
    } else {
      #pragma unroll
      for (int j = 0; j < 48; ++j) eeL[lane][j] = 0.0f;
    }
  }
  unsigned long long mb = __ballot(mval > 0.5f); // step-active bits, SGPR pair

  bf16x8 Af[3][2];                              // static A = expT^T frags
  const unsigned short* eta = bw + BW_ETA;
  #pragma unroll
  for (int mt = 0; mt < 3; ++mt)
    #pragma unroll
    for (int kt = 0; kt < 2; ++kt)
      Af[mt][kt] = *(const bf16x8*)(eta + (mt * 16 + l15) * 64 + kt * 32 + q * 8);

  float Clog = 0.0f;
  __syncthreads();

  for (int tt = 0; tt < 32; ++tt) {
    if ((mb >> tt) & 1ull) {                    // SALU bit test, wave-uniform
      bf16x8 Bf[2][3];
      #pragma unroll
      for (int kt = 0; kt < 2; ++kt)
        #pragma unroll
        for (int nt = 0; nt < 3; ++nt)
          Bf[kt][nt] = *(const bf16x8*)&S[nt * 16 + l15][kt * 32 + q * 8];
      f32x4 acc[3][3];
      f32x4 z4 = {0.f, 0.f, 0.f, 0.f};
      #pragma unroll
      for (int mt = 0; mt < 3; ++mt)
        #pragma unroll
        for (int nt = 0; nt < 3; ++nt) {
          acc[mt][nt] = __builtin_amdgcn_mfma_f32_16x16x32_bf16(
              Af[mt][0], Bf[0][nt], z4, 0, 0, 0);
          acc[mt][nt] = __builtin_amdgcn_mfma_f32_16x16x32_bf16(
              Af[mt][1], Bf[1][nt], acc[mt][nt], 0, 0, 0);
        }
      float r = rfl(acc[0][0][0]);              // D[0][0] = P_new[0][0] > 0
      float rin = __builtin_amdgcn_rcpf(r);
      float Cadd = __logf(r);
      #pragma unroll
      for (int mt = 0; mt < 3; ++mt) {
        f32x4 e4 = *(const f32x4*)&eeL[tt][mt * 16 + q * 4];
        e4 = e4 * rin;                          // combined col-scale * renorm
        #pragma unroll
        for (int nt = 0; nt < 3; ++nt) {
          f32x4 v = acc[mt][nt] * e4;
          uint2 pk;
          pk.x = pk_bf16(v[0], v[1]);
          pk.y = pk_bf16(v[2], v[3]);
          *(uint2*)&S[nt * 16 + l15][mt * 16 + q * 4] = pk;
        }
      }
      Clog += Cadd;
      __syncthreads();                          // 1 wave: waitcnt + barrier
    }
  }

  __syncthreads();
  float* Pb = Pmat + (size_t)(b * NC + c) * (NP * NP);
  #pragma unroll
  for (int i = 0; i < 9; ++i) {                 // dump S -> f32 Pmat
    int flat = i * 64 + lane;                   // 0..575 float4 slots
    int n = flat / 12, qq = flat - n * 12;
    unsigned long long pk = *(unsigned long long*)&S[n][qq * 4];
    float4 o;
    o.x = bf2f((unsigned short)(pk));
    o.y = bf2f((unsigned short)(pk >> 16));
    o.z = bf2f((unsigned short)(pk >> 32));
    o.w = bf2f((unsigned short)(pk >> 48));
    *(float4*)&Pb[n * 48 + qq * 4] = o;
  }
  if (lane == 0) CC[b * NC + c] = Clog;
}

// ---------------- per-batch serial combine: Z_b ------------------------------
__global__ __launch_bounds__(64) void reduceZ(
    const float* __restrict__ logits, const float* __restrict__ bos,
    const float* __restrict__ T, const float* __restrict__ Pmat,
    const float* __restrict__ CC, float* __restrict__ Zarr) {
  __shared__ float shv[64];
  const int b = blockIdx.x, lane = threadIdx.x;
  float a0;
  if (lane < 33)       a0 = logits[(size_t)b * SS * 33 + lane] + T[BOSR * NT + lane];
  else if (lane == 33) a0 = bos[(size_t)b * SS] + T[BOSR * NT + 33];
  else                 a0 = -INFINITY;
  float K = rfl(a0);                            // lane0 finite
  float v = (lane < 48) ? __expf(a0 - K) : 0.0f;
  float C = K;
  for (int c = 0; c < NC; ++c) {
    shv[lane] = v;
    __syncthreads();
    float u = 0.0f;
    if (lane < 48) {
      const float* Pr = Pmat + (size_t)(b * NC + c) * (NP * NP) + lane * 48;
      float uu0 = 0.f, uu1 = 0.f, uu2 = 0.f, uu3 = 0.f;   // 4-way dep-chain split
      #pragma unroll
      for (int qq = 0; qq < 12; qq += 4) {
        float4 p0 = *(const float4*)(Pr + qq * 4);
        float4 p1 = *(const float4*)(Pr + qq * 4 + 4);
        float4 p2 = *(const float4*)(Pr + qq * 4 + 8);
        float4 p3 = *(const float4*)(Pr + qq * 4 + 12);
        float4 v0 = *(const float4*)&shv[qq * 4];
        float4 v1 = *(const float4*)&shv[qq * 4 + 4];
        float4 v2 = *(const float4*)&shv[qq * 4 + 8];
        float4 v3 = *(const float4*)&shv[qq * 4 + 12];
        uu0 = fmaf(p0.x, v0.x, uu0); uu0 = fmaf(p0.y, v0.y, uu0);
        uu0 = fmaf(p0.z, v0.z, uu0); uu0 = fmaf(p0.w, v0.w, uu0);
        uu1 = fmaf(p1.x, v1.x, uu1); uu1 = fmaf(p1.y, v1.y, uu1);
        uu1 = fmaf(p1.z, v1.z, uu1); uu1 = fmaf(p1.w, v1.w, uu1);
        uu2 = fmaf(p2.x, v2.x, uu2); uu2 = fmaf(p2.y, v2.y, uu2);
        uu2 = fmaf(p2.z, v2.z, uu2); uu2 = fmaf(p2.w, v2.w, uu2);
        uu3 = fmaf(p3.x, v3.x, uu3); uu3 = fmaf(p3.y, v3.y, uu3);
        uu3 = fmaf(p3.w, v3.w, uu3); uu3 = fmaf(p3.z, v3.z, uu3);
      }
      u = (uu0 + uu1) + (uu2 + uu3);
    }
    float r = rfl(u);                           // lane0: u > 0
    v = u * __builtin_amdgcn_rcpf(r);
    C += __logf(r) + CC[b * NC + c];
    __syncthreads();
  }
  float s = warp_sum64(v);
  if (lane == 0) Zarr[b] = C + __logf(s);
}

// ---------------- final: loss = sum_b (Z_b - score_b) ------------------------
__global__ void finalk(const float* __restrict__ Zarr,
                       const float* __restrict__ sc, float* __restrict__ out) {
  float x = Zarr[threadIdx.x] - sc[threadIdx.x];
  float s = warp_sum64(x);
  if (threadIdx.x == 0) out[0] = s;
}

extern "C" void kernel_launch(void* const* d_in, const int* in_sizes, int n_in,
                              void* d_out, int out_size, void* d_ws, size_t ws_size,
                              hipStream_t stream) {
  const float* em   = (const float*)d_in[0];
  const int*   tags = (const int*)d_in[1];
  const float* mask = (const float*)d_in[2];
  const float* W    = (const float*)d_in[3];
  const float* bias = (const float*)d_in[4];
  const float* T    = (const float*)d_in[5];

  float* out = (float*)d_out;
  float* ws  = (float*)d_ws;
  float* bos   = ws + WS_BOS;
  float* Pmat  = ws + WS_PMAT;
  float* CC    = ws + WS_CC;
  float* Zarr  = ws + WS_Z;
  float* score = ws + WS_SC;
  unsigned short* bw = (unsigned short*)(ws + WS_BF16);
  float* logits = out + 1;                      // d_out = [loss, logits(B,S,33)]

  hipLaunchKernelGGL(prep, dim3(204), dim3(256), 0, stream, W, T, bw);
  hipLaunchKernelGGL(gemm_mfma, dim3(NB * SS / 128), dim3(256), 0, stream,
                     em, bw, bias, logits, bos);
  hipLaunchKernelGGL(chains_mat, dim3(NB * NC + NB), dim3(64), 0, stream,
                     logits, bos, bw, mask, T, tags, Pmat, CC, score);
  hipLaunchKernelGGL(reduceZ, dim3(NB), dim3(64), 0, stream,
                     logits, bos, T, Pmat, CC, Zarr);
  hipLaunchKernelGGL(finalk, dim3(1), dim3(64), 0, stream, Zarr, score, out);
}